// Round 4
// baseline (979.626 us; speedup 1.0000x reference)
//
#include <hip/hip_runtime.h>

// ---------------------------------------------------------------------------
// Decoder: B=8 T=512 D=1024 H=16 DH=64 L=4 C=10.
// Round 6: resubmission of Round 5 (bench infra failed: "container failed
// twice" is broker-level; kernel audit found no OOB/race/divergent-barrier).
//  - attn: 128-key chunks (half the barriers / shfl-reduces / rescales per
//    key), V staged via packed ds_write_b64, PV in two 64-key halves, P
//    buffer aliases the Q tile (LDS 40 KB -> 4 blocks/CU preserved).
//  - ordinal head fused into last fc GEMM epilogue (mode 3): removes
//    head_k dispatch + 16 MB re-read + dead cur write.
//  - carried from R4: XCD-bijective swizzles, gemm64 2/CU, fused QKV GEMM,
//    merged casts.
// ---------------------------------------------------------------------------

#define BB   8
#define TT   512
#define DD   1024
#define HH   16
#define DHH  64
#define LLAY 4
#define MM   (BB*TT)          // 4096 rows
#define MD   ((size_t)MM*DD)  // 4,194,304 elements
#define INV_RD (1.0f/32.0f)   // 1/sqrt(D)
#define LNEPS 1e-5f

typedef unsigned short ushort_t;
typedef __attribute__((ext_vector_type(8))) short short8;
typedef __attribute__((ext_vector_type(4))) float floatx4;

__device__ inline ushort_t f2bf(float f) {
  unsigned u = __builtin_bit_cast(unsigned, f);
  unsigned r = (u + 0x7FFFu + ((u >> 16) & 1u)) >> 16;  // RNE
  return (ushort_t)r;
}

// One kernel, 8 segments of 4M fp32 elements each (1M float4 / segment):
//  seg 0..2 : Wq1/Wk1/Wv1 [L,1024,1024] -> fused wqkv [L][3072][1024]
//  seg 3,4  : Wq2, Wfc -> linear bf16
//  seg 5,6  : kin, vin -> linear bf16
//  seg 7    : x + pos -> cur (fp32) + act_bf (bf16)
__global__ __launch_bounds__(256) void cast_all_k(
    const float* __restrict__ Wq1, const float* __restrict__ Wk1,
    const float* __restrict__ Wv1, const float* __restrict__ Wq2f,
    const float* __restrict__ Wfcf, const float* __restrict__ kin,
    const float* __restrict__ vin, const float* __restrict__ x,
    const float* __restrict__ pos,
    ushort_t* __restrict__ wqkv, ushort_t* __restrict__ wq2,
    ushort_t* __restrict__ wfc, ushort_t* __restrict__ kinbf,
    ushort_t* __restrict__ vinbf, float* __restrict__ cur,
    ushort_t* __restrict__ act_bf) {
  int seg = blockIdx.x >> 12;
  size_t j = ((size_t)(blockIdx.x & 4095)) * 256 + threadIdx.x;  // float4 idx
  if (seg == 7) {
    int dq  = (int)(j & 255);
    int row = (int)(j >> 8);
    int t   = row & (TT - 1);
    float4 a = ((const float4*)x)[j];
    float4 p = ((const float4*)pos)[(size_t)t * 256 + dq];
    a.x += p.x; a.y += p.y; a.z += p.z; a.w += p.w;
    ((float4*)cur)[j] = a;
    ushort4 b; b.x = f2bf(a.x); b.y = f2bf(a.y); b.z = f2bf(a.z); b.w = f2bf(a.w);
    ((ushort4*)act_bf)[j] = b;
    return;
  }
  const float* src;
  switch (seg) {
    case 0: src = Wq1; break;
    case 1: src = Wk1; break;
    case 2: src = Wv1; break;
    case 3: src = Wq2f; break;
    case 4: src = Wfcf; break;
    case 5: src = kin; break;
    default: src = vin; break;
  }
  float4 v = ((const float4*)src)[j];
  ushort4 o; o.x = f2bf(v.x); o.y = f2bf(v.y); o.z = f2bf(v.z); o.w = f2bf(v.w);
  if (seg < 3) {
    int d4 = (int)(j & 255);
    int n  = (int)((j >> 8) & 1023);
    int i  = (int)(j >> 18);
    size_t drow = (size_t)i * 3072 + (size_t)seg * 1024 + n;
    ((ushort4*)wqkv)[drow * 256 + d4] = o;
  } else {
    ushort_t* dst = (seg == 3) ? wq2 : (seg == 4) ? wfc : (seg == 5) ? kinbf : vinbf;
    ((ushort4*)dst)[j] = o;
  }
}

// LayerNorm: one block per row of D=1024; writes fp32 + bf16 copies.
__global__ __launch_bounds__(256) void ln_k(const float* __restrict__ in,
                                            float* __restrict__ out,
                                            ushort_t* __restrict__ out_bf,
                                            const float* __restrict__ g,
                                            const float* __restrict__ bt) {
  int row = blockIdx.x;
  int t = threadIdx.x;
  const float4* r4 = (const float4*)(in + (size_t)row * DD);
  float4 v = r4[t];
  float s  = v.x + v.y + v.z + v.w;
  float ss = v.x*v.x + v.y*v.y + v.z*v.z + v.w*v.w;
#pragma unroll
  for (int off = 32; off > 0; off >>= 1) {
    s  += __shfl_down(s, off);
    ss += __shfl_down(ss, off);
  }
  __shared__ float red[8];
  int w = t >> 6;
  if ((t & 63) == 0) { red[w] = s; red[4 + w] = ss; }
  __syncthreads();
  s  = red[0] + red[1] + red[2] + red[3];
  ss = red[4] + red[5] + red[6] + red[7];
  float mean = s * (1.0f / DD);
  float var  = ss * (1.0f / DD) - mean * mean;
  float inv  = rsqrtf(var + LNEPS);
  float4 gv = ((const float4*)g)[t];
  float4 bv = ((const float4*)bt)[t];
  float4 o;
  o.x = (v.x - mean) * inv * gv.x + bv.x;
  o.y = (v.y - mean) * inv * gv.y + bv.y;
  o.z = (v.z - mean) * inv * gv.z + bv.z;
  o.w = (v.w - mean) * inv * gv.w + bv.w;
  ((float4*)(out + (size_t)row * DD))[t] = o;
  ushort4 ob; ob.x = f2bf(o.x); ob.y = f2bf(o.y); ob.z = f2bf(o.z); ob.w = f2bf(o.w);
  ((ushort4*)(out_bf + (size_t)row * DD))[t] = ob;
}

// 128x128 tile GEMM (m97 structure): C[m,n] = sum_k A[m,k]*W[n,k].
// Used for the fused QKV GEMM (N=3072): bf16 out, 1024-col segments routed
// to contiguous [MM,DD] buffers at Cout + seg*MD. 1D grid, XCD-bijective
// swizzle (nwg = nbx*nby must be %8==0).
__global__ __launch_bounds__(256) void gemm_mfma_bt_k(const ushort_t* __restrict__ A,
                                                      const ushort_t* __restrict__ W,
                                                      ushort_t* __restrict__ Cout,
                                                      int nbx) {
  __shared__ ushort_t As[128 * 32];
  __shared__ ushort_t Bs[128 * 32];
  int t = threadIdx.x;
  int d = blockIdx.x;
  int chunk = gridDim.x >> 3;
  int logical = (d & 7) * chunk + (d >> 3);
  int bx = logical % nbx, by = logical / nbx;
  int n0 = bx * 128, m0 = by * 128;
  int lane = t & 63, w = t >> 6;
  int wm = (w >> 1) * 64, wn = (w & 1) * 64;
  int fr = lane & 15, q = lane >> 4;
  const short8* ap[4]; const short8* bp[4];
#pragma unroll
  for (int i = 0; i < 4; i++) {
    int r  = wm + i * 16 + fr;
    int rn = wn + i * 16 + fr;
    ap[i] = (const short8*)(As + r  * 32 + ((q ^ ((r  >> 1) & 3)) * 8));
    bp[i] = (const short8*)(Bs + rn * 32 + ((q ^ ((rn >> 1) & 3)) * 8));
  }
  auto* As3 = (__attribute__((address_space(3))) ushort_t*)As;
  auto* Bs3 = (__attribute__((address_space(3))) ushort_t*)Bs;
  floatx4 acc[4][4] = {};
  for (int k0 = 0; k0 < DD; k0 += 32) {
    __syncthreads();
#pragma unroll
    for (int j = 0; j < 2; j++) {
      int e = t + j * 256;
      int row = e >> 2, slot = e & 3;
      int c = slot ^ ((row >> 1) & 3);
      const ushort_t* asrc = A + (size_t)(m0 + row) * DD + k0 + c * 8;
      const ushort_t* wsrc = W + (size_t)(n0 + row) * DD + k0 + c * 8;
      __builtin_amdgcn_global_load_lds(
          (const __attribute__((address_space(1))) unsigned*)asrc,
          (__attribute__((address_space(3))) unsigned*)(As3 + e * 8), 16, 0, 0);
      __builtin_amdgcn_global_load_lds(
          (const __attribute__((address_space(1))) unsigned*)wsrc,
          (__attribute__((address_space(3))) unsigned*)(Bs3 + e * 8), 16, 0, 0);
    }
    __syncthreads();
    short8 af[4], bf[4];
#pragma unroll
    for (int i = 0; i < 4; i++) { af[i] = *ap[i]; bf[i] = *bp[i]; }
#pragma unroll
    for (int i = 0; i < 4; i++)
#pragma unroll
      for (int j = 0; j < 4; j++)
        acc[i][j] = __builtin_amdgcn_mfma_f32_16x16x32_bf16(af[i], bf[j], acc[i][j], 0, 0, 0);
  }
  int orow = m0 + wm + q * 4;
  int ocol = n0 + wn + fr;
  int seg = n0 >> 10;
  ushort_t* Cb = Cout + (size_t)seg * MD;
#pragma unroll
  for (int i = 0; i < 4; i++)
#pragma unroll
    for (int j = 0; j < 4; j++)
#pragma unroll
      for (int rr = 0; rr < 4; rr++)
        Cb[(size_t)(orow + i * 16 + rr) * DD + ((ocol + j * 16) & 1023)] =
            f2bf(acc[i][j][rr]);
}

// 128x64 tile GEMM for N=1024 (grid 512 = 2 blocks/CU).
// mode 1: bf16 out. mode 2: fp32 fc epilogue C = relu(acc+bias)+lnres.
// mode 3: fc epilogue + ordinal sigmoid head -> headout[idx*10..+10].
__global__ __launch_bounds__(256) void gemm64_k(const ushort_t* __restrict__ A,
                                                const ushort_t* __restrict__ W,
                                                void* __restrict__ Cout,
                                                const float* __restrict__ bias,
                                                const float* __restrict__ lnres,
                                                const float* __restrict__ cutv,
                                                int mode) {
  __shared__ ushort_t As[128 * 32];
  __shared__ ushort_t Bs[64 * 32];
  int t = threadIdx.x;
  int d = blockIdx.x;                 // nwg = 512, chunk = 64
  int logical = (d & 7) * 64 + (d >> 3);
  int bx = logical & 15, by = logical >> 4;   // nbx=16 (n), nby=32 (m)
  int n0 = bx * 64, m0 = by * 128;
  int lane = t & 63, w = t >> 6;
  int wm = (w >> 1) * 64, wn = (w & 1) * 32;
  int fr = lane & 15, q = lane >> 4;
  const short8* ap[4]; const short8* bp[2];
#pragma unroll
  for (int i = 0; i < 4; i++) {
    int r = wm + i * 16 + fr;
    ap[i] = (const short8*)(As + r * 32 + ((q ^ ((r >> 1) & 3)) * 8));
  }
#pragma unroll
  for (int j = 0; j < 2; j++) {
    int rn = wn + j * 16 + fr;
    bp[j] = (const short8*)(Bs + rn * 32 + ((q ^ ((rn >> 1) & 3)) * 8));
  }
  auto* As3 = (__attribute__((address_space(3))) ushort_t*)As;
  auto* Bs3 = (__attribute__((address_space(3))) ushort_t*)Bs;
  floatx4 acc[4][2] = {};
  for (int k0 = 0; k0 < DD; k0 += 32) {
    __syncthreads();
#pragma unroll
    for (int j = 0; j < 2; j++) {
      int e = t + j * 256;
      int row = e >> 2, slot = e & 3;
      int c = slot ^ ((row >> 1) & 3);
      const ushort_t* asrc = A + (size_t)(m0 + row) * DD + k0 + c * 8;
      __builtin_amdgcn_global_load_lds(
          (const __attribute__((address_space(1))) unsigned*)asrc,
          (__attribute__((address_space(3))) unsigned*)(As3 + e * 8), 16, 0, 0);
    }
    {
      int e = t;
      int row = e >> 2, slot = e & 3;
      int c = slot ^ ((row >> 1) & 3);
      const ushort_t* wsrc = W + (size_t)(n0 + row) * DD + k0 + c * 8;
      __builtin_amdgcn_global_load_lds(
          (const __attribute__((address_space(1))) unsigned*)wsrc,
          (__attribute__((address_space(3))) unsigned*)(Bs3 + e * 8), 16, 0, 0);
    }
    __syncthreads();
    short8 af[4], bf[2];
#pragma unroll
    for (int i = 0; i < 4; i++) af[i] = *ap[i];
#pragma unroll
    for (int j = 0; j < 2; j++) bf[j] = *bp[j];
#pragma unroll
    for (int i = 0; i < 4; i++)
#pragma unroll
      for (int j = 0; j < 2; j++)
        acc[i][j] = __builtin_amdgcn_mfma_f32_16x16x32_bf16(af[i], bf[j], acc[i][j], 0, 0, 0);
  }
  int orow = m0 + wm + q * 4;
  if (mode == 1) {
    ushort_t* Cb = (ushort_t*)Cout;
#pragma unroll
    for (int i = 0; i < 4; i++)
#pragma unroll
      for (int j = 0; j < 2; j++) {
        int colg = n0 + wn + j * 16 + fr;
#pragma unroll
        for (int rr = 0; rr < 4; rr++)
          Cb[(size_t)(orow + i * 16 + rr) * DD + colg] = f2bf(acc[i][j][rr]);
      }
  } else if (mode == 2) {  // fc epilogue
    float* C = (float*)Cout;
#pragma unroll
    for (int j = 0; j < 2; j++) {
      int colg = n0 + wn + j * 16 + fr;
      float bv = bias[colg];
#pragma unroll
      for (int i = 0; i < 4; i++)
#pragma unroll
        for (int rr = 0; rr < 4; rr++) {
          size_t idx = (size_t)(orow + i * 16 + rr) * DD + colg;
          C[idx] = fmaxf(acc[i][j][rr] + bv, 0.f) + lnres[idx];
        }
    }
  } else {  // mode 3: fc epilogue + ordinal sigmoid head
    float* H = (float*)Cout;
    float bcum[9];
    bcum[0] = cutv[0];
#pragma unroll
    for (int j = 1; j < 9; j++) { float c = cutv[j]; bcum[j] = bcum[j - 1] + c * c; }
#pragma unroll
    for (int j = 0; j < 2; j++) {
      int colg = n0 + wn + j * 16 + fr;
      float bv = bias[colg];
#pragma unroll
      for (int i = 0; i < 4; i++)
#pragma unroll
        for (int rr = 0; rr < 4; rr++) {
          size_t idx = (size_t)(orow + i * 16 + rr) * DD + colg;
          float xv = fmaxf(acc[i][j][rr] + bv, 0.f) + lnres[idx];
          float ov[10];
          float sp = 1.0f / (1.0f + __expf(xv - bcum[0]));
          ov[0] = sp;
#pragma unroll
          for (int c = 1; c < 9; c++) {
            float sc = 1.0f / (1.0f + __expf(xv - bcum[c]));
            ov[c] = sc - sp;
            sp = sc;
          }
          ov[9] = 1.0f - sp;
          float2* op = (float2*)(H + idx * 10);   // idx*10 even -> 8B aligned
#pragma unroll
          for (int c = 0; c < 5; c++) { float2 p; p.x = ov[2 * c]; p.y = ov[2 * c + 1]; op[c] = p; }
        }
    }
  }
}

// Flash attention, bf16 MFMA, KVBLK=128. 1D grid of 1024 with XCD-bijective
// swizzle (XCD x owns 16 consecutive bh -> K/V L2-resident across q-tiles).
// Block: 64 q rows of one (b,h); wave w owns q rows [w*16,+16).
// K chunks of 128 keys: K natural [key][dh] LDS (XOR chunk swizzle),
// V transposed [dh][key] LDS (packed ds_write_b64). Online softmax in
// registers; PV in two 64-key halves through a wave-private P buffer that
// ALIASES the Q tile LDS (Q only read pre-loop; chunk-0 barrier separates).
// cross=1: K/V layout (B,H,T,DH), triangular chunk skip, key>q mask on the
// last (diagonal) chunk. Output: resid + O, fp32.
__global__ __launch_bounds__(256) void attn_mfma_k(const ushort_t* __restrict__ Qb,
                                                   const ushort_t* __restrict__ Kb,
                                                   const ushort_t* __restrict__ Vb,
                                                   const float* __restrict__ resid,
                                                   float* __restrict__ out,
                                                   int cross) {
  __shared__ ushort_t Ks[128 * 64];   // 16 KB
  __shared__ ushort_t Vts[64 * 128];  // 16 KB
  __shared__ ushort_t QP[64 * 64];    // 8 KB: Q tile (prologue) / P bufs (loop)
  int t = threadIdx.x, lane = t & 63, w = t >> 6;
  int fr = lane & 15, q8 = lane >> 4;
  int dsp = blockIdx.x;                       // nwg = 1024, chunk = 128
  int logical = (dsp & 7) * 128 + (dsp >> 3);
  int qt = logical & 7, bh = logical >> 3;
  int b = bh >> 4, h = bh & 15;
  size_t qbase = ((size_t)(b * TT + qt * 64)) * DD + h * DHH;
  size_t kvbase; int kvstride;
  if (cross) { kvbase = (size_t)bh * TT * DHH;          kvstride = DHH; }
  else       { kvbase = (size_t)b * TT * DD + h * DHH;  kvstride = DD;  }

  auto* QP3 = (__attribute__((address_space(3))) ushort_t*)QP;
  auto* Ks3 = (__attribute__((address_space(3))) ushort_t*)Ks;

  // stage Q tile (64 rows x 8 chunks of 8 bf16), source-side swizzle
#pragma unroll
  for (int j = 0; j < 2; j++) {
    int e = t + j * 256;
    int row = e >> 3, slot = e & 7;
    int c = slot ^ (row & 7);
    const ushort_t* src = Qb + qbase + (size_t)row * DD + c * 8;
    __builtin_amdgcn_global_load_lds(
        (const __attribute__((address_space(1))) unsigned*)src,
        (__attribute__((address_space(3))) unsigned*)(QP3 + e * 8), 16, 0, 0);
  }
  __syncthreads();

  // Q A-fragments: lane holds Q[w*16 + fr][q8*8 + ks*32 .. +8]
  short8 qf[2];
#pragma unroll
  for (int ks = 0; ks < 2; ks++) {
    int row = w * 16 + fr;
    int slot = (ks * 4 + q8) ^ (row & 7);
    qf[ks] = *(const short8*)(QP + row * 64 + slot * 8);
  }

  float m_i[4], l_i[4];
  floatx4 o_acc[4] = {};
#pragma unroll
  for (int r = 0; r < 4; r++) { m_i[r] = -1e30f; l_i[r] = 0.f; }

  int nch = cross ? ((qt * 64 + 64 + 127) >> 7) : (TT / 128);
  for (int ch = 0; ch < nch; ch++) {
    __syncthreads();   // prior chunk's K/V/P traffic done; also fences Q reads
    // stage K chunk: 128 rows x 64 dh
#pragma unroll
    for (int j = 0; j < 4; j++) {
      int e = t + j * 256;
      int row = e >> 3, slot = e & 7;
      int c = slot ^ (row & 7);
      const ushort_t* src = Kb + kvbase + (size_t)(ch * 128 + row) * kvstride + c * 8;
      __builtin_amdgcn_global_load_lds(
          (const __attribute__((address_space(1))) unsigned*)src,
          (__attribute__((address_space(3))) unsigned*)(Ks3 + e * 8), 16, 0, 0);
    }
    // stage V transposed [dh][key]: thread owns keys {4kp..4kp+3} x 8 dh,
    // packed pair writes (ds_write_b64). slot16 = (key>>3) ^ (dh&15).
    {
      int kp = t & 31, dhg = (t >> 5) * 8;
      const ushort_t* v0 = Vb + kvbase + (size_t)(ch * 128 + 4 * kp) * kvstride + dhg;
      short8 a0 = *(const short8*)v0;
      short8 a1 = *(const short8*)(v0 + kvstride);
      short8 a2 = *(const short8*)(v0 + 2 * kvstride);
      short8 a3 = *(const short8*)(v0 + 3 * kvstride);
#pragma unroll
      for (int j = 0; j < 8; j++) {
        int dh = dhg + j;
        int slot = (kp >> 1) ^ (dh & 15);
        unsigned p01 = (unsigned)(unsigned short)a0[j] |
                       ((unsigned)(unsigned short)a1[j] << 16);
        unsigned p23 = (unsigned)(unsigned short)a2[j] |
                       ((unsigned)(unsigned short)a3[j] << 16);
        uint2 pk; pk.x = p01; pk.y = p23;
        *(uint2*)(Vts + dh * 128 + slot * 8 + (kp & 1) * 4) = pk;
      }
    }
    __syncthreads();

    // S = Q K^T (per wave: 16 q x 128 keys), scale, mask
    floatx4 s[8] = {};
    __builtin_amdgcn_s_setprio(1);
#pragma unroll
    for (int nt = 0; nt < 8; nt++) {
      int key = nt * 16 + fr;
#pragma unroll
      for (int ks = 0; ks < 2; ks++) {
        int slot = (ks * 4 + q8) ^ (key & 7);
        short8 kf = *(const short8*)(Ks + key * 64 + slot * 8);
        s[nt] = __builtin_amdgcn_mfma_f32_16x16x32_bf16(qf[ks], kf, s[nt], 0, 0, 0);
      }
    }
    __builtin_amdgcn_s_setprio(0);
    float sv[8][4];
#pragma unroll
    for (int nt = 0; nt < 8; nt++)
#pragma unroll
      for (int r = 0; r < 4; r++)
        sv[nt][r] = s[nt][r] * INV_RD;
    if (cross && ch == nch - 1) {
#pragma unroll
      for (int nt = 0; nt < 8; nt++) {
        int key_g = ch * 128 + nt * 16 + fr;
#pragma unroll
        for (int r = 0; r < 4; r++) {
          int q_g = qt * 64 + w * 16 + q8 * 4 + r;
          if (key_g > q_g) sv[nt][r] = -1e30f;
        }
      }
    }

    // online softmax update (rows = q8*4+r, reduce across 16 fr lanes);
    // exp values overwrite sv in place.
#pragma unroll
    for (int r = 0; r < 4; r++) {
      float mch = fmaxf(fmaxf(fmaxf(sv[0][r], sv[1][r]), fmaxf(sv[2][r], sv[3][r])),
                        fmaxf(fmaxf(sv[4][r], sv[5][r]), fmaxf(sv[6][r], sv[7][r])));
#pragma unroll
      for (int off = 1; off < 16; off <<= 1) mch = fmaxf(mch, __shfl_xor(mch, off));
      float mn = fmaxf(m_i[r], mch);
      float alpha = __expf(m_i[r] - mn);
      m_i[r] = mn;
      float rs = 0.f;
#pragma unroll
      for (int nt = 0; nt < 8; nt++) {
        float pe = __expf(sv[nt][r] - mn);
        sv[nt][r] = pe; rs += pe;
      }
#pragma unroll
      for (int off = 1; off < 16; off <<= 1) rs += __shfl_xor(rs, off);
      l_i[r] = l_i[r] * alpha + rs;
#pragma unroll
      for (int nt = 0; nt < 4; nt++) o_acc[nt][r] *= alpha;
    }

    // P -> LDS (wave-private, aliases Q tile) in two 64-key halves; PV MFMA.
    ushort_t* Pw = QP + w * 1024;
#pragma unroll
    for (int hf = 0; hf < 2; hf++) {
#pragma unroll
      for (int n4 = 0; n4 < 4; n4++) {
        int col = n4 * 16 + fr;
#pragma unroll
        for (int r = 0; r < 4; r++) {
          int row = q8 * 4 + r;
          int slot = (col >> 3) ^ (row & 7);
          Pw[row * 64 + slot * 8 + (col & 7)] = f2bf(sv[hf * 4 + n4][r]);
        }
      }
      short8 pf[2];
#pragma unroll
      for (int ks = 0; ks < 2; ks++) {
        int slot = (ks * 4 + q8) ^ (fr & 7);
        pf[ks] = *(const short8*)(Pw + fr * 64 + slot * 8);
      }
      __builtin_amdgcn_s_setprio(1);
#pragma unroll
      for (int dnt = 0; dnt < 4; dnt++) {
        int dh = dnt * 16 + fr;
#pragma unroll
        for (int ks = 0; ks < 2; ks++) {
          int vslot = (hf * 8 + ks * 4 + q8) ^ (dh & 15);
          short8 vf = *(const short8*)(Vts + dh * 128 + vslot * 8);
          o_acc[dnt] = __builtin_amdgcn_mfma_f32_16x16x32_bf16(pf[ks], vf, o_acc[dnt], 0, 0, 0);
        }
      }
      __builtin_amdgcn_s_setprio(0);
    }
  }

  // epilogue: O/l + residual
  float invl[4];
#pragma unroll
  for (int r = 0; r < 4; r++) invl[r] = 1.0f / l_i[r];
#pragma unroll
  for (int nt = 0; nt < 4; nt++) {
#pragma unroll
    for (int r = 0; r < 4; r++) {
      size_t row_g = (size_t)(b * TT + qt * 64 + w * 16 + q8 * 4 + r);
      size_t idx = row_g * DD + h * DHH + nt * 16 + fr;
      out[idx] = resid[idx] + o_acc[nt][r] * invl[r];
    }
  }
}

extern "C" void kernel_launch(void* const* d_in, const int* in_sizes, int n_in,
                              void* d_out, int out_size, void* d_ws, size_t ws_size,
                              hipStream_t stream) {
  (void)in_sizes; (void)n_in; (void)out_size; (void)ws_size;
  const float* x    = (const float*)d_in[0];
  const float* kin  = (const float*)d_in[1];
  const float* vin  = (const float*)d_in[2];
  const float* pos  = (const float*)d_in[3];
  const float* Wq1  = (const float*)d_in[4];
  const float* Wk1  = (const float*)d_in[5];
  const float* Wv1  = (const float*)d_in[6];
  const float* Wq2  = (const float*)d_in[7];
  const float* Wfc  = (const float*)d_in[8];
  const float* bfc  = (const float*)d_in[9];
  const float* g1   = (const float*)d_in[10];
  const float* b1   = (const float*)d_in[11];
  const float* g2   = (const float*)d_in[12];
  const float* b2   = (const float*)d_in[13];
  const float* g3   = (const float*)d_in[14];
  const float* b3   = (const float*)d_in[15];
  const float* cut  = (const float*)d_in[16];
  float* out = (float*)d_out;

  // ws (120 MB): cur 16 | tmp 16 | act_bf 8 | qkv_bf 24 | kinbf 8 | vinbf 8
  //              | wqkv 24 | wq2 8 | wfc 8
  float* cur = (float*)d_ws;
  float* tmp = cur + MD;
  ushort_t* act_bf = (ushort_t*)(tmp + MD);
  ushort_t* qbf    = act_bf + MD;     // qkv_bf base: q | k | v contiguous
  ushort_t* kbf    = qbf + MD;
  ushort_t* vbf    = kbf + MD;
  ushort_t* kinbf  = vbf + MD;
  ushort_t* vinbf  = kinbf + MD;
  ushort_t* wqkv   = vinbf + MD;                               // [L][3072][1024]
  ushort_t* wq2    = wqkv + (size_t)LLAY * 3 * DD * DD;        // [L][1024][1024]
  ushort_t* wfc    = wq2  + (size_t)LLAY * DD * DD;

  dim3 b256(256);

  cast_all_k<<<8 * 4096, b256, 0, stream>>>(Wq1, Wk1, Wv1, Wq2, Wfc, kin, vin,
                                            x, pos, wqkv, wq2, wfc, kinbf, vinbf,
                                            cur, act_bf);

  for (int i = 0; i < LLAY; i++) {
    const float* attn_in;
    if (i) {
      ln_k<<<MM, b256, 0, stream>>>(cur, tmp, act_bf,
                                    g1 + (size_t)(i - 1) * DD, b1 + (size_t)(i - 1) * DD);
      attn_in = tmp;
    } else {
      attn_in = cur;   // act_bf already holds bf16(cur)
    }
    // fused QKV GEMM: N=3072, outputs routed to qbf/kbf/vbf; 768 blocks
    gemm_mfma_bt_k<<<768, b256, 0, stream>>>(act_bf, wqkv + (size_t)i * 3 * DD * DD,
                                             qbf, 24);
    attn_mfma_k<<<1024, b256, 0, stream>>>(qbf, kbf, vbf, attn_in, cur, 0);

    ln_k<<<MM, b256, 0, stream>>>(cur, tmp, act_bf,
                                  g2 + (size_t)i * DD, b2 + (size_t)i * DD);
    gemm64_k<<<512, b256, 0, stream>>>(act_bf, wq2 + (size_t)i * DD * DD,
                                       qbf, nullptr, nullptr, nullptr, 1);
    attn_mfma_k<<<1024, b256, 0, stream>>>(qbf, kinbf, vinbf, tmp, cur, 1);

    ln_k<<<MM, b256, 0, stream>>>(cur, tmp, act_bf,
                                  g3 + (size_t)i * DD, b3 + (size_t)i * DD);
    if (i < LLAY - 1) {
      // fc GEMM with fused bias+relu+residual epilogue -> cur (fp32)
      gemm64_k<<<512, b256, 0, stream>>>(act_bf, wfc + (size_t)i * DD * DD,
                                         cur, bfc + (size_t)i * DD, tmp, nullptr, 2);
    } else {
      // last layer: fc epilogue + ordinal head fused -> out
      gemm64_k<<<512, b256, 0, stream>>>(act_bf, wfc + (size_t)i * DD * DD,
                                         out, bfc + (size_t)i * DD, tmp, cut, 3);
    }
  }
}

// Round 5
// 942.797 us; speedup vs baseline: 1.0391x; 1.0391x over previous
//
#include <hip/hip_runtime.h>

// ---------------------------------------------------------------------------
// Decoder: B=8 T=512 D=1024 H=16 DH=64 L=4 C=10.
// Round 7: BK=64 GEMMs + BHTD intermediate layout.
//  - Both GEMMs: K-step 32->64 (half the barriers). 64-wide LDS rows with
//    the same XOR-slot swizzle attn already uses for Q/K (proven pattern).
//  - qbf/kbf/vbf now [BH][T][DH] bf16: GEMM epilogues scatter-route (free,
//    they were 2B scatters anyway); attn staging becomes fully contiguous
//    (was stride-1024 gathers). Self/cross attn share one stride-64 path.
//  - carried: XCD swizzles, fused QKV GEMM, head fusion (mode 3), KVBLK=128.
// ---------------------------------------------------------------------------

#define BB   8
#define TT   512
#define DD   1024
#define HH   16
#define DHH  64
#define LLAY 4
#define MM   (BB*TT)          // 4096 rows
#define MD   ((size_t)MM*DD)  // 4,194,304 elements
#define INV_RD (1.0f/32.0f)   // 1/sqrt(D)
#define LNEPS 1e-5f

typedef unsigned short ushort_t;
typedef __attribute__((ext_vector_type(8))) short short8;
typedef __attribute__((ext_vector_type(4))) float floatx4;

__device__ inline ushort_t f2bf(float f) {
  unsigned u = __builtin_bit_cast(unsigned, f);
  unsigned r = (u + 0x7FFFu + ((u >> 16) & 1u)) >> 16;  // RNE
  return (ushort_t)r;
}

// BHTD index for token m (0..4095) and feature col cg (0..1023).
__device__ inline size_t bhtd(int m, int cg) {
  return ((size_t)((m >> 9) * HH + (cg >> 6)) * TT + (m & (TT - 1))) * DHH + (cg & 63);
}

// One kernel, 8 segments of 4M fp32 elements each (1M float4 / segment):
//  seg 0..2 : Wq1/Wk1/Wv1 [L,1024,1024] -> fused wqkv [L][3072][1024]
//  seg 3,4  : Wq2, Wfc -> linear bf16
//  seg 5,6  : kin, vin -> linear bf16 (input layout is already [B,H,T,DH])
//  seg 7    : x + pos -> cur (fp32) + act_bf (bf16)
__global__ __launch_bounds__(256) void cast_all_k(
    const float* __restrict__ Wq1, const float* __restrict__ Wk1,
    const float* __restrict__ Wv1, const float* __restrict__ Wq2f,
    const float* __restrict__ Wfcf, const float* __restrict__ kin,
    const float* __restrict__ vin, const float* __restrict__ x,
    const float* __restrict__ pos,
    ushort_t* __restrict__ wqkv, ushort_t* __restrict__ wq2,
    ushort_t* __restrict__ wfc, ushort_t* __restrict__ kinbf,
    ushort_t* __restrict__ vinbf, float* __restrict__ cur,
    ushort_t* __restrict__ act_bf) {
  int seg = blockIdx.x >> 12;
  size_t j = ((size_t)(blockIdx.x & 4095)) * 256 + threadIdx.x;  // float4 idx
  if (seg == 7) {
    int dq  = (int)(j & 255);
    int row = (int)(j >> 8);
    int t   = row & (TT - 1);
    float4 a = ((const float4*)x)[j];
    float4 p = ((const float4*)pos)[(size_t)t * 256 + dq];
    a.x += p.x; a.y += p.y; a.z += p.z; a.w += p.w;
    ((float4*)cur)[j] = a;
    ushort4 b; b.x = f2bf(a.x); b.y = f2bf(a.y); b.z = f2bf(a.z); b.w = f2bf(a.w);
    ((ushort4*)act_bf)[j] = b;
    return;
  }
  const float* src;
  switch (seg) {
    case 0: src = Wq1; break;
    case 1: src = Wk1; break;
    case 2: src = Wv1; break;
    case 3: src = Wq2f; break;
    case 4: src = Wfcf; break;
    case 5: src = kin; break;
    default: src = vin; break;
  }
  float4 v = ((const float4*)src)[j];
  ushort4 o; o.x = f2bf(v.x); o.y = f2bf(v.y); o.z = f2bf(v.z); o.w = f2bf(v.w);
  if (seg < 3) {
    int d4 = (int)(j & 255);
    int n  = (int)((j >> 8) & 1023);
    int i  = (int)(j >> 18);
    size_t drow = (size_t)i * 3072 + (size_t)seg * 1024 + n;
    ((ushort4*)wqkv)[drow * 256 + d4] = o;
  } else {
    ushort_t* dst = (seg == 3) ? wq2 : (seg == 4) ? wfc : (seg == 5) ? kinbf : vinbf;
    ((ushort4*)dst)[j] = o;
  }
}

// LayerNorm: one block per row of D=1024; writes fp32 + bf16 copies.
__global__ __launch_bounds__(256) void ln_k(const float* __restrict__ in,
                                            float* __restrict__ out,
                                            ushort_t* __restrict__ out_bf,
                                            const float* __restrict__ g,
                                            const float* __restrict__ bt) {
  int row = blockIdx.x;
  int t = threadIdx.x;
  const float4* r4 = (const float4*)(in + (size_t)row * DD);
  float4 v = r4[t];
  float s  = v.x + v.y + v.z + v.w;
  float ss = v.x*v.x + v.y*v.y + v.z*v.z + v.w*v.w;
#pragma unroll
  for (int off = 32; off > 0; off >>= 1) {
    s  += __shfl_down(s, off);
    ss += __shfl_down(ss, off);
  }
  __shared__ float red[8];
  int w = t >> 6;
  if ((t & 63) == 0) { red[w] = s; red[4 + w] = ss; }
  __syncthreads();
  s  = red[0] + red[1] + red[2] + red[3];
  ss = red[4] + red[5] + red[6] + red[7];
  float mean = s * (1.0f / DD);
  float var  = ss * (1.0f / DD) - mean * mean;
  float inv  = rsqrtf(var + LNEPS);
  float4 gv = ((const float4*)g)[t];
  float4 bv = ((const float4*)bt)[t];
  float4 o;
  o.x = (v.x - mean) * inv * gv.x + bv.x;
  o.y = (v.y - mean) * inv * gv.y + bv.y;
  o.z = (v.z - mean) * inv * gv.z + bv.z;
  o.w = (v.w - mean) * inv * gv.w + bv.w;
  ((float4*)(out + (size_t)row * DD))[t] = o;
  ushort4 ob; ob.x = f2bf(o.x); ob.y = f2bf(o.y); ob.z = f2bf(o.z); ob.w = f2bf(o.w);
  ((ushort4*)(out_bf + (size_t)row * DD))[t] = ob;
}

// 128x128 tile GEMM, BK=64: C[m,n] = sum_k A[m,k]*W[n,k]. Fused QKV GEMM
// (N=3072): bf16 out routed to BHTD buffers at Cout + seg*MD (seg=n0>>10).
// 1D grid, XCD-bijective swizzle (nwg % 8 == 0).
__global__ __launch_bounds__(256) void gemm_mfma_bt_k(const ushort_t* __restrict__ A,
                                                      const ushort_t* __restrict__ W,
                                                      ushort_t* __restrict__ Cout,
                                                      int nbx) {
  __shared__ ushort_t As[128 * 64];   // 16 KB
  __shared__ ushort_t Bs[128 * 64];   // 16 KB
  int t = threadIdx.x;
  int d = blockIdx.x;
  int chunk = gridDim.x >> 3;
  int logical = (d & 7) * chunk + (d >> 3);
  int bx = logical % nbx, by = logical / nbx;
  int n0 = bx * 128, m0 = by * 128;
  int lane = t & 63, w = t >> 6;
  int wm = (w >> 1) * 64, wn = (w & 1) * 64;
  int fr = lane & 15, q = lane >> 4;
  int arow[4], brow[4];
#pragma unroll
  for (int i = 0; i < 4; i++) { arow[i] = wm + i * 16 + fr; brow[i] = wn + i * 16 + fr; }
  auto* As3 = (__attribute__((address_space(3))) ushort_t*)As;
  auto* Bs3 = (__attribute__((address_space(3))) ushort_t*)Bs;
  floatx4 acc[4][4] = {};
  for (int k0 = 0; k0 < DD; k0 += 64) {
    __syncthreads();
#pragma unroll
    for (int j = 0; j < 4; j++) {
      int e = t + j * 256;
      int row = e >> 3, slot = e & 7;
      int c = slot ^ (row & 7);
      const ushort_t* asrc = A + (size_t)(m0 + row) * DD + k0 + c * 8;
      const ushort_t* wsrc = W + (size_t)(n0 + row) * DD + k0 + c * 8;
      __builtin_amdgcn_global_load_lds(
          (const __attribute__((address_space(1))) unsigned*)asrc,
          (__attribute__((address_space(3))) unsigned*)(As3 + e * 8), 16, 0, 0);
      __builtin_amdgcn_global_load_lds(
          (const __attribute__((address_space(1))) unsigned*)wsrc,
          (__attribute__((address_space(3))) unsigned*)(Bs3 + e * 8), 16, 0, 0);
    }
    __syncthreads();
#pragma unroll
    for (int kk = 0; kk < 2; kk++) {
      short8 af[4], bf[4];
#pragma unroll
      for (int i = 0; i < 4; i++) {
        int ra = arow[i], rb = brow[i];
        af[i] = *(const short8*)(As + ra * 64 + (((kk * 4 + q) ^ (ra & 7)) * 8));
        bf[i] = *(const short8*)(Bs + rb * 64 + (((kk * 4 + q) ^ (rb & 7)) * 8));
      }
#pragma unroll
      for (int i = 0; i < 4; i++)
#pragma unroll
        for (int j = 0; j < 4; j++)
          acc[i][j] = __builtin_amdgcn_mfma_f32_16x16x32_bf16(af[i], bf[j], acc[i][j], 0, 0, 0);
    }
  }
  int orow = m0 + wm + q * 4;
  int ocol = n0 + wn + fr;
  int seg = n0 >> 10;
  ushort_t* Cb = Cout + (size_t)seg * MD;
#pragma unroll
  for (int i = 0; i < 4; i++)
#pragma unroll
    for (int j = 0; j < 4; j++) {
      int cg = (ocol + j * 16) & 1023;
#pragma unroll
      for (int rr = 0; rr < 4; rr++)
        Cb[bhtd(orow + i * 16 + rr, cg)] = f2bf(acc[i][j][rr]);
    }
}

// 128x64 tile GEMM, BK=64, N=1024 (grid 512 = 2 blocks/CU).
// mode 1: bf16 BHTD out (cross-attn Q). mode 2: fp32 fc epilogue
// C = relu(acc+bias)+lnres. mode 3: fc epilogue + ordinal head.
__global__ __launch_bounds__(256) void gemm64_k(const ushort_t* __restrict__ A,
                                                const ushort_t* __restrict__ W,
                                                void* __restrict__ Cout,
                                                const float* __restrict__ bias,
                                                const float* __restrict__ lnres,
                                                const float* __restrict__ cutv,
                                                int mode) {
  __shared__ ushort_t As[128 * 64];   // 16 KB
  __shared__ ushort_t Bs[64 * 64];    //  8 KB
  int t = threadIdx.x;
  int d = blockIdx.x;                 // nwg = 512, chunk = 64
  int logical = (d & 7) * 64 + (d >> 3);
  int bx = logical & 15, by = logical >> 4;   // nbx=16 (n), nby=32 (m)
  int n0 = bx * 64, m0 = by * 128;
  int lane = t & 63, w = t >> 6;
  int wm = (w >> 1) * 64, wn = (w & 1) * 32;
  int fr = lane & 15, q = lane >> 4;
  int arow[4], brow[2];
#pragma unroll
  for (int i = 0; i < 4; i++) arow[i] = wm + i * 16 + fr;
#pragma unroll
  for (int j = 0; j < 2; j++) brow[j] = wn + j * 16 + fr;
  auto* As3 = (__attribute__((address_space(3))) ushort_t*)As;
  auto* Bs3 = (__attribute__((address_space(3))) ushort_t*)Bs;
  floatx4 acc[4][2] = {};
  for (int k0 = 0; k0 < DD; k0 += 64) {
    __syncthreads();
#pragma unroll
    for (int j = 0; j < 4; j++) {
      int e = t + j * 256;
      int row = e >> 3, slot = e & 7;
      int c = slot ^ (row & 7);
      const ushort_t* asrc = A + (size_t)(m0 + row) * DD + k0 + c * 8;
      __builtin_amdgcn_global_load_lds(
          (const __attribute__((address_space(1))) unsigned*)asrc,
          (__attribute__((address_space(3))) unsigned*)(As3 + e * 8), 16, 0, 0);
    }
#pragma unroll
    for (int j = 0; j < 2; j++) {
      int e = t + j * 256;
      int row = e >> 3, slot = e & 7;
      int c = slot ^ (row & 7);
      const ushort_t* wsrc = W + (size_t)(n0 + row) * DD + k0 + c * 8;
      __builtin_amdgcn_global_load_lds(
          (const __attribute__((address_space(1))) unsigned*)wsrc,
          (__attribute__((address_space(3))) unsigned*)(Bs3 + e * 8), 16, 0, 0);
    }
    __syncthreads();
#pragma unroll
    for (int kk = 0; kk < 2; kk++) {
      short8 af[4], bf[2];
#pragma unroll
      for (int i = 0; i < 4; i++) {
        int ra = arow[i];
        af[i] = *(const short8*)(As + ra * 64 + (((kk * 4 + q) ^ (ra & 7)) * 8));
      }
#pragma unroll
      for (int j = 0; j < 2; j++) {
        int rb = brow[j];
        bf[j] = *(const short8*)(Bs + rb * 64 + (((kk * 4 + q) ^ (rb & 7)) * 8));
      }
#pragma unroll
      for (int i = 0; i < 4; i++)
#pragma unroll
        for (int j = 0; j < 2; j++)
          acc[i][j] = __builtin_amdgcn_mfma_f32_16x16x32_bf16(af[i], bf[j], acc[i][j], 0, 0, 0);
    }
  }
  int orow = m0 + wm + q * 4;
  if (mode == 1) {
    ushort_t* Cb = (ushort_t*)Cout;
#pragma unroll
    for (int i = 0; i < 4; i++)
#pragma unroll
      for (int j = 0; j < 2; j++) {
        int colg = n0 + wn + j * 16 + fr;
#pragma unroll
        for (int rr = 0; rr < 4; rr++)
          Cb[bhtd(orow + i * 16 + rr, colg)] = f2bf(acc[i][j][rr]);
      }
  } else if (mode == 2) {  // fc epilogue
    float* C = (float*)Cout;
#pragma unroll
    for (int j = 0; j < 2; j++) {
      int colg = n0 + wn + j * 16 + fr;
      float bv = bias[colg];
#pragma unroll
      for (int i = 0; i < 4; i++)
#pragma unroll
        for (int rr = 0; rr < 4; rr++) {
          size_t idx = (size_t)(orow + i * 16 + rr) * DD + colg;
          C[idx] = fmaxf(acc[i][j][rr] + bv, 0.f) + lnres[idx];
        }
    }
  } else {  // mode 3: fc epilogue + ordinal sigmoid head
    float* H = (float*)Cout;
    float bcum[9];
    bcum[0] = cutv[0];
#pragma unroll
    for (int j = 1; j < 9; j++) { float c = cutv[j]; bcum[j] = bcum[j - 1] + c * c; }
#pragma unroll
    for (int j = 0; j < 2; j++) {
      int colg = n0 + wn + j * 16 + fr;
      float bv = bias[colg];
#pragma unroll
      for (int i = 0; i < 4; i++)
#pragma unroll
        for (int rr = 0; rr < 4; rr++) {
          size_t idx = (size_t)(orow + i * 16 + rr) * DD + colg;
          float xv = fmaxf(acc[i][j][rr] + bv, 0.f) + lnres[idx];
          float ov[10];
          float sp = 1.0f / (1.0f + __expf(xv - bcum[0]));
          ov[0] = sp;
#pragma unroll
          for (int c = 1; c < 9; c++) {
            float sc = 1.0f / (1.0f + __expf(xv - bcum[c]));
            ov[c] = sc - sp;
            sp = sc;
          }
          ov[9] = 1.0f - sp;
          float2* op = (float2*)(H + idx * 10);   // idx*10 even -> 8B aligned
#pragma unroll
          for (int c = 0; c < 5; c++) { float2 p; p.x = ov[2 * c]; p.y = ov[2 * c + 1]; op[c] = p; }
        }
    }
  }
}

// Flash attention, bf16 MFMA, KVBLK=128, BHTD operands (stride 64 always).
// 1D grid of 1024, XCD-bijective swizzle. Block: 64 q rows of one (b,h).
// K natural [key][dh] LDS, V transposed [dh][key] LDS, P aliases Q tile.
// cross=1 only controls chunk count + diagonal mask.
__global__ __launch_bounds__(256) void attn_mfma_k(const ushort_t* __restrict__ Qb,
                                                   const ushort_t* __restrict__ Kb,
                                                   const ushort_t* __restrict__ Vb,
                                                   const float* __restrict__ resid,
                                                   float* __restrict__ out,
                                                   int cross) {
  __shared__ ushort_t Ks[128 * 64];   // 16 KB
  __shared__ ushort_t Vts[64 * 128];  // 16 KB
  __shared__ ushort_t QP[64 * 64];    // 8 KB: Q tile (prologue) / P bufs (loop)
  int t = threadIdx.x, lane = t & 63, w = t >> 6;
  int fr = lane & 15, q8 = lane >> 4;
  int dsp = blockIdx.x;                       // nwg = 1024, chunk = 128
  int logical = (dsp & 7) * 128 + (dsp >> 3);
  int qt = logical & 7, bh = logical >> 3;
  int b = bh >> 4, h = bh & 15;
  size_t kvbase = (size_t)bh * TT * DHH;
  size_t qbase  = kvbase + (size_t)qt * 64 * DHH;

  auto* QP3 = (__attribute__((address_space(3))) ushort_t*)QP;
  auto* Ks3 = (__attribute__((address_space(3))) ushort_t*)Ks;

  // stage Q tile (64 rows x 8 chunks of 8 bf16), contiguous source
#pragma unroll
  for (int j = 0; j < 2; j++) {
    int e = t + j * 256;
    int row = e >> 3, slot = e & 7;
    int c = slot ^ (row & 7);
    const ushort_t* src = Qb + qbase + (size_t)row * 64 + c * 8;
    __builtin_amdgcn_global_load_lds(
        (const __attribute__((address_space(1))) unsigned*)src,
        (__attribute__((address_space(3))) unsigned*)(QP3 + e * 8), 16, 0, 0);
  }
  __syncthreads();

  // Q A-fragments: lane holds Q[w*16 + fr][q8*8 + ks*32 .. +8]
  short8 qf[2];
#pragma unroll
  for (int ks = 0; ks < 2; ks++) {
    int row = w * 16 + fr;
    int slot = (ks * 4 + q8) ^ (row & 7);
    qf[ks] = *(const short8*)(QP + row * 64 + slot * 8);
  }

  float m_i[4], l_i[4];
  floatx4 o_acc[4] = {};
#pragma unroll
  for (int r = 0; r < 4; r++) { m_i[r] = -1e30f; l_i[r] = 0.f; }

  int nch = cross ? ((qt * 64 + 64 + 127) >> 7) : (TT / 128);
  for (int ch = 0; ch < nch; ch++) {
    __syncthreads();   // prior chunk's K/V/P traffic done; also fences Q reads
    // stage K chunk: 128 rows x 64 dh, contiguous
#pragma unroll
    for (int j = 0; j < 4; j++) {
      int e = t + j * 256;
      int row = e >> 3, slot = e & 7;
      int c = slot ^ (row & 7);
      const ushort_t* src = Kb + kvbase + (size_t)(ch * 128 + row) * 64 + c * 8;
      __builtin_amdgcn_global_load_lds(
          (const __attribute__((address_space(1))) unsigned*)src,
          (__attribute__((address_space(3))) unsigned*)(Ks3 + e * 8), 16, 0, 0);
    }
    // stage V transposed [dh][key]: thread owns keys {4kp..4kp+3} x 8 dh,
    // packed pair writes (ds_write_b64). slot16 = (key>>3) ^ (dh&15).
    {
      int kp = t & 31, dhg = (t >> 5) * 8;
      const ushort_t* v0 = Vb + kvbase + (size_t)(ch * 128 + 4 * kp) * 64 + dhg;
      short8 a0 = *(const short8*)v0;
      short8 a1 = *(const short8*)(v0 + 64);
      short8 a2 = *(const short8*)(v0 + 128);
      short8 a3 = *(const short8*)(v0 + 192);
#pragma unroll
      for (int j = 0; j < 8; j++) {
        int dh = dhg + j;
        int slot = (kp >> 1) ^ (dh & 15);
        unsigned p01 = (unsigned)(unsigned short)a0[j] |
                       ((unsigned)(unsigned short)a1[j] << 16);
        unsigned p23 = (unsigned)(unsigned short)a2[j] |
                       ((unsigned)(unsigned short)a3[j] << 16);
        uint2 pk; pk.x = p01; pk.y = p23;
        *(uint2*)(Vts + dh * 128 + slot * 8 + (kp & 1) * 4) = pk;
      }
    }
    __syncthreads();

    // S = Q K^T (per wave: 16 q x 128 keys), scale, mask
    floatx4 s[8] = {};
    __builtin_amdgcn_s_setprio(1);
#pragma unroll
    for (int nt = 0; nt < 8; nt++) {
      int key = nt * 16 + fr;
#pragma unroll
      for (int ks = 0; ks < 2; ks++) {
        int slot = (ks * 4 + q8) ^ (key & 7);
        short8 kf = *(const short8*)(Ks + key * 64 + slot * 8);
        s[nt] = __builtin_amdgcn_mfma_f32_16x16x32_bf16(qf[ks], kf, s[nt], 0, 0, 0);
      }
    }
    __builtin_amdgcn_s_setprio(0);
    float sv[8][4];
#pragma unroll
    for (int nt = 0; nt < 8; nt++)
#pragma unroll
      for (int r = 0; r < 4; r++)
        sv[nt][r] = s[nt][r] * INV_RD;
    if (cross && ch == nch - 1) {
#pragma unroll
      for (int nt = 0; nt < 8; nt++) {
        int key_g = ch * 128 + nt * 16 + fr;
#pragma unroll
        for (int r = 0; r < 4; r++) {
          int q_g = qt * 64 + w * 16 + q8 * 4 + r;
          if (key_g > q_g) sv[nt][r] = -1e30f;
        }
      }
    }

    // online softmax update (rows = q8*4+r, reduce across 16 fr lanes);
    // exp values overwrite sv in place.
#pragma unroll
    for (int r = 0; r < 4; r++) {
      float mch = fmaxf(fmaxf(fmaxf(sv[0][r], sv[1][r]), fmaxf(sv[2][r], sv[3][r])),
                        fmaxf(fmaxf(sv[4][r], sv[5][r]), fmaxf(sv[6][r], sv[7][r])));
#pragma unroll
      for (int off = 1; off < 16; off <<= 1) mch = fmaxf(mch, __shfl_xor(mch, off));
      float mn = fmaxf(m_i[r], mch);
      float alpha = __expf(m_i[r] - mn);
      m_i[r] = mn;
      float rs = 0.f;
#pragma unroll
      for (int nt = 0; nt < 8; nt++) {
        float pe = __expf(sv[nt][r] - mn);
        sv[nt][r] = pe; rs += pe;
      }
#pragma unroll
      for (int off = 1; off < 16; off <<= 1) rs += __shfl_xor(rs, off);
      l_i[r] = l_i[r] * alpha + rs;
#pragma unroll
      for (int nt = 0; nt < 4; nt++) o_acc[nt][r] *= alpha;
    }

    // P -> LDS (wave-private, aliases Q tile) in two 64-key halves; PV MFMA.
    ushort_t* Pw = QP + w * 1024;
#pragma unroll
    for (int hf = 0; hf < 2; hf++) {
#pragma unroll
      for (int n4 = 0; n4 < 4; n4++) {
        int col = n4 * 16 + fr;
#pragma unroll
        for (int r = 0; r < 4; r++) {
          int row = q8 * 4 + r;
          int slot = (col >> 3) ^ (row & 7);
          Pw[row * 64 + slot * 8 + (col & 7)] = f2bf(sv[hf * 4 + n4][r]);
        }
      }
      short8 pf[2];
#pragma unroll
      for (int ks = 0; ks < 2; ks++) {
        int slot = (ks * 4 + q8) ^ (fr & 7);
        pf[ks] = *(const short8*)(Pw + fr * 64 + slot * 8);
      }
      __builtin_amdgcn_s_setprio(1);
#pragma unroll
      for (int dnt = 0; dnt < 4; dnt++) {
        int dh = dnt * 16 + fr;
#pragma unroll
        for (int ks = 0; ks < 2; ks++) {
          int vslot = (hf * 8 + ks * 4 + q8) ^ (dh & 15);
          short8 vf = *(const short8*)(Vts + dh * 128 + vslot * 8);
          o_acc[dnt] = __builtin_amdgcn_mfma_f32_16x16x32_bf16(pf[ks], vf, o_acc[dnt], 0, 0, 0);
        }
      }
      __builtin_amdgcn_s_setprio(0);
    }
  }

  // epilogue: O/l + residual (residual stream stays [B,T,D] fp32)
  float invl[4];
#pragma unroll
  for (int r = 0; r < 4; r++) invl[r] = 1.0f / l_i[r];
#pragma unroll
  for (int nt = 0; nt < 4; nt++) {
#pragma unroll
    for (int r = 0; r < 4; r++) {
      size_t row_g = (size_t)(b * TT + qt * 64 + w * 16 + q8 * 4 + r);
      size_t idx = row_g * DD + h * DHH + nt * 16 + fr;
      out[idx] = resid[idx] + o_acc[nt][r] * invl[r];
    }
  }
}

extern "C" void kernel_launch(void* const* d_in, const int* in_sizes, int n_in,
                              void* d_out, int out_size, void* d_ws, size_t ws_size,
                              hipStream_t stream) {
  (void)in_sizes; (void)n_in; (void)out_size; (void)ws_size;
  const float* x    = (const float*)d_in[0];
  const float* kin  = (const float*)d_in[1];
  const float* vin  = (const float*)d_in[2];
  const float* pos  = (const float*)d_in[3];
  const float* Wq1  = (const float*)d_in[4];
  const float* Wk1  = (const float*)d_in[5];
  const float* Wv1  = (const float*)d_in[6];
  const float* Wq2  = (const float*)d_in[7];
  const float* Wfc  = (const float*)d_in[8];
  const float* bfc  = (const float*)d_in[9];
  const float* g1   = (const float*)d_in[10];
  const float* b1   = (const float*)d_in[11];
  const float* g2   = (const float*)d_in[12];
  const float* b2   = (const float*)d_in[13];
  const float* g3   = (const float*)d_in[14];
  const float* b3   = (const float*)d_in[15];
  const float* cut  = (const float*)d_in[16];
  float* out = (float*)d_out;

  // ws (120 MB): cur 16 | tmp 16 | act_bf 8 | qkv_bf 24 | kinbf 8 | vinbf 8
  //              | wqkv 24 | wq2 8 | wfc 8
  float* cur = (float*)d_ws;
  float* tmp = cur + MD;
  ushort_t* act_bf = (ushort_t*)(tmp + MD);
  ushort_t* qbf    = act_bf + MD;     // qkv_bf base: q | k | v contiguous (BHTD)
  ushort_t* kbf    = qbf + MD;
  ushort_t* vbf    = kbf + MD;
  ushort_t* kinbf  = vbf + MD;
  ushort_t* vinbf  = kinbf + MD;
  ushort_t* wqkv   = vinbf + MD;                               // [L][3072][1024]
  ushort_t* wq2    = wqkv + (size_t)LLAY * 3 * DD * DD;        // [L][1024][1024]
  ushort_t* wfc    = wq2  + (size_t)LLAY * DD * DD;

  dim3 b256(256);

  cast_all_k<<<8 * 4096, b256, 0, stream>>>(Wq1, Wk1, Wv1, Wq2, Wfc, kin, vin,
                                            x, pos, wqkv, wq2, wfc, kinbf, vinbf,
                                            cur, act_bf);

  for (int i = 0; i < LLAY; i++) {
    const float* attn_in;
    if (i) {
      ln_k<<<MM, b256, 0, stream>>>(cur, tmp, act_bf,
                                    g1 + (size_t)(i - 1) * DD, b1 + (size_t)(i - 1) * DD);
      attn_in = tmp;
    } else {
      attn_in = cur;   // act_bf already holds bf16(cur)
    }
    // fused QKV GEMM: N=3072, outputs routed to qbf/kbf/vbf (BHTD); 768 blocks
    gemm_mfma_bt_k<<<768, b256, 0, stream>>>(act_bf, wqkv + (size_t)i * 3 * DD * DD,
                                             qbf, 24);
    attn_mfma_k<<<1024, b256, 0, stream>>>(qbf, kbf, vbf, attn_in, cur, 0);

    ln_k<<<MM, b256, 0, stream>>>(cur, tmp, act_bf,
                                  g2 + (size_t)i * DD, b2 + (size_t)i * DD);
    gemm64_k<<<512, b256, 0, stream>>>(act_bf, wq2 + (size_t)i * DD * DD,
                                       qbf, nullptr, nullptr, nullptr, 1);
    attn_mfma_k<<<1024, b256, 0, stream>>>(qbf, kinbf, vinbf, tmp, cur, 1);

    ln_k<<<MM, b256, 0, stream>>>(cur, tmp, act_bf,
                                  g3 + (size_t)i * DD, b3 + (size_t)i * DD);
    if (i < LLAY - 1) {
      // fc GEMM with fused bias+relu+residual epilogue -> cur (fp32)
      gemm64_k<<<512, b256, 0, stream>>>(act_bf, wfc + (size_t)i * DD * DD,
                                         cur, bfc + (size_t)i * DD, tmp, nullptr, 2);
    } else {
      // last layer: fc epilogue + ordinal head fused -> out
      gemm64_k<<<512, b256, 0, stream>>>(act_bf, wfc + (size_t)i * DD * DD,
                                         out, bfc + (size_t)i * DD, tmp, cut, 3);
    }
  }
}